// Round 1
// baseline (663.671 us; speedup 1.0000x reference)
//
#include <hip/hip_runtime.h>

typedef __bf16 bf16;
typedef __attribute__((ext_vector_type(8))) __bf16 bf16x8;
typedef __attribute__((ext_vector_type(4))) float f32x4;

#define T 128
#define DIM 4096
#define NACT 11468
#define A_PAD 11520   // 360 tiles of 32
#define KCH 2880      // phase-2 K chunk (A_PAD/4)

// ---------------- pre-kernel: x fp32 -> bf16 ----------------
__global__ __launch_bounds__(256) void k_cvt_x(const float* __restrict__ x,
                                               bf16* __restrict__ xb) {
  int i = (blockIdx.x * 256 + threadIdx.x) * 8;
  f32x4 a = *(const f32x4*)(x + i);
  f32x4 b = *(const f32x4*)(x + i + 4);
  bf16x8 o;
  o[0] = (bf16)a[0]; o[1] = (bf16)a[1]; o[2] = (bf16)a[2]; o[3] = (bf16)a[3];
  o[4] = (bf16)b[0]; o[5] = (bf16)b[1]; o[6] = (bf16)b[2]; o[7] = (bf16)b[3];
  *(bf16x8*)(xb + i) = o;
}

// ---------------- phase 1: g_e = silu(x w1^T) * (x w3^T) * ew_e ----------------
// block = 256 threads = 4 waves: wave = (wm in {0,1}) x (wn in {0,1})
// wave computes M=64 (rows wm*64..) x N=16 (cols bx*32 + wn*16 ..)
__global__ __launch_bounds__(256) void k_phase1(
    const bf16* __restrict__ xb,
    const float* __restrict__ w1e0, const float* __restrict__ w3e0,
    const float* __restrict__ w1e1, const float* __restrict__ w3e1,
    const float* __restrict__ ew, const int* __restrict__ ids,
    bf16* __restrict__ gws) {
  const int e = blockIdx.y;
  const float* __restrict__ w1 = e ? w1e1 : w1e0;
  const float* __restrict__ w3 = e ? w3e1 : w3e0;
  bf16* __restrict__ g = gws + (size_t)e * T * A_PAD;

  const int tid = threadIdx.x;
  const int wave = tid >> 6;
  const int lane = tid & 63;
  const int ln = lane & 15;     // fragment row index (a for B, t for A)
  const int kh = lane >> 4;     // k-half group (0..3), 8 elems each
  const int wm = wave >> 1;     // m half
  const int wn = wave & 1;      // n 16-group

  const int arow = blockIdx.x * 32 + wn * 16 + ln;
  const int arow_c = arow < NACT ? arow : NACT - 1;  // clamp loads, mask stores

  const float* __restrict__ p1 = w1 + (size_t)arow_c * DIM + kh * 8;
  const float* __restrict__ p3 = w3 + (size_t)arow_c * DIM + kh * 8;
  const bf16* __restrict__ px = xb + (size_t)(wm * 64 + ln) * DIM + kh * 8;

  f32x4 accu[4], accg[4];
#pragma unroll
  for (int m = 0; m < 4; ++m) {
    accu[m] = (f32x4){0.f, 0.f, 0.f, 0.f};
    accg[m] = (f32x4){0.f, 0.f, 0.f, 0.f};
  }

  for (int k0 = 0; k0 < DIM; k0 += 32) {
    f32x4 l1a = *(const f32x4*)(p1 + k0);
    f32x4 l1b = *(const f32x4*)(p1 + k0 + 4);
    f32x4 l3a = *(const f32x4*)(p3 + k0);
    f32x4 l3b = *(const f32x4*)(p3 + k0 + 4);
    bf16x8 f1, f3;
    f1[0] = (bf16)l1a[0]; f1[1] = (bf16)l1a[1]; f1[2] = (bf16)l1a[2]; f1[3] = (bf16)l1a[3];
    f1[4] = (bf16)l1b[0]; f1[5] = (bf16)l1b[1]; f1[6] = (bf16)l1b[2]; f1[7] = (bf16)l1b[3];
    f3[0] = (bf16)l3a[0]; f3[1] = (bf16)l3a[1]; f3[2] = (bf16)l3a[2]; f3[3] = (bf16)l3a[3];
    f3[4] = (bf16)l3b[0]; f3[5] = (bf16)l3b[1]; f3[6] = (bf16)l3b[2]; f3[7] = (bf16)l3b[3];

    bf16x8 xa[4];
#pragma unroll
    for (int m = 0; m < 4; ++m)
      xa[m] = *(const bf16x8*)(px + (size_t)m * 16 * DIM + k0);

#pragma unroll
    for (int m = 0; m < 4; ++m) {
      accu[m] = __builtin_amdgcn_mfma_f32_16x16x32_bf16(xa[m], f3, accu[m], 0, 0, 0);
      accg[m] = __builtin_amdgcn_mfma_f32_16x16x32_bf16(xa[m], f1, accg[m], 0, 0, 0);
    }
  }

  // routing weights (swap if incoming expert_ids[0] != 0)
  float e0 = ew[0], e1 = ew[1];
  if (ids[0] != 0) { float t = e0; e0 = e1; e1 = t; }
  const float sel = e ? e1 : e0;
  const bool valid = arow < NACT;

#pragma unroll
  for (int m = 0; m < 4; ++m) {
#pragma unroll
    for (int j = 0; j < 4; ++j) {
      int t = wm * 64 + m * 16 + kh * 4 + j;  // C/D: row=(lane>>4)*4+reg, col=lane&15
      float up = accu[m][j];
      float gt = accg[m][j];
      float sg = gt / (1.f + __expf(-gt));
      float val = valid ? sg * up * sel : 0.f;
      g[(size_t)t * A_PAD + arow] = (bf16)val;
    }
  }
}

// ---------------- phase 2: out += sum_e g_e @ w2_e  (split-K, atomic fp32) ----------------
// block = 256 = 4 waves (wm x wn); wave: M=64 x N=16; grid (DIM/32, 2 experts * 4 kchunks)
__global__ __launch_bounds__(256) void k_phase2(
    const bf16* __restrict__ gws,
    const float* __restrict__ w2e0, const float* __restrict__ w2e1,
    float* __restrict__ out) {
  const int e = blockIdx.y >> 2;
  const int kc = blockIdx.y & 3;
  const float* __restrict__ w2 = e ? w2e1 : w2e0;
  const bf16* __restrict__ g = gws + (size_t)e * T * A_PAD;

  const int tid = threadIdx.x;
  const int wave = tid >> 6;
  const int lane = tid & 63;
  const int ln = lane & 15;
  const int kh = lane >> 4;
  const int wm = wave >> 1;
  const int wn = wave & 1;

  const int dcol = blockIdx.x * 32 + wn * 16 + ln;
  const int kbase = kc * KCH;
  const bool chunk_safe = (kbase + KCH) <= NACT;  // only last chunk needs clamping

  f32x4 acc[4];
#pragma unroll
  for (int m = 0; m < 4; ++m) acc[m] = (f32x4){0.f, 0.f, 0.f, 0.f};

  const bf16* __restrict__ pg = g + (size_t)(wm * 64 + ln) * A_PAD + kh * 8;
  const float* __restrict__ pw = w2 + dcol;

  for (int k0 = kbase; k0 < kbase + KCH; k0 += 32) {
    bf16x8 ga[4];
#pragma unroll
    for (int m = 0; m < 4; ++m)
      ga[m] = *(const bf16x8*)(pg + (size_t)m * 16 * A_PAD + k0);

    bf16x8 bw;
    const int kr = k0 + kh * 8;
    if (chunk_safe || kr + 7 < NACT) {
      const float* p = pw + (size_t)kr * DIM;
#pragma unroll
      for (int j = 0; j < 8; ++j) bw[j] = (bf16)p[(size_t)j * DIM];
    } else {
#pragma unroll
      for (int j = 0; j < 8; ++j) {
        int k = kr + j;
        int kcl = k < NACT ? k : NACT - 1;  // g is 0 in pad region, product is 0
        bw[j] = (bf16)pw[(size_t)kcl * DIM];
      }
    }

#pragma unroll
    for (int m = 0; m < 4; ++m)
      acc[m] = __builtin_amdgcn_mfma_f32_16x16x32_bf16(ga[m], bw, acc[m], 0, 0, 0);
  }

#pragma unroll
  for (int m = 0; m < 4; ++m) {
#pragma unroll
    for (int j = 0; j < 4; ++j) {
      int t = wm * 64 + m * 16 + kh * 4 + j;
      atomicAdd(out + (size_t)t * DIM + dcol, acc[m][j]);
    }
  }
}

// ---------------- launch ----------------
extern "C" void kernel_launch(void* const* d_in, const int* in_sizes, int n_in,
                              void* d_out, int out_size, void* d_ws, size_t ws_size,
                              hipStream_t stream) {
  const float* x    = (const float*)d_in[0];
  const float* ew   = (const float*)d_in[1];
  const int*   ids  = (const int*)d_in[2];
  const float* w1e0 = (const float*)d_in[3];
  const float* w3e0 = (const float*)d_in[4];
  const float* w2e0 = (const float*)d_in[5];
  const float* w1e1 = (const float*)d_in[6];
  const float* w3e1 = (const float*)d_in[7];
  const float* w2e1 = (const float*)d_in[8];
  float* out = (float*)d_out;

  bf16* xb = (bf16*)d_ws;                                   // 128*4096*2 = 1 MB
  bf16* g  = (bf16*)((char*)d_ws + (size_t)T * DIM * 2);    // 2 * 128*11520*2 = 5.9 MB

  hipMemsetAsync(d_out, 0, (size_t)T * DIM * sizeof(float), stream);
  k_cvt_x<<<dim3((T * DIM) / (256 * 8)), 256, 0, stream>>>(x, xb);
  k_phase1<<<dim3(A_PAD / 32, 2), 256, 0, stream>>>(xb, w1e0, w3e0, w1e1, w3e1, ew, ids, g);
  k_phase2<<<dim3(DIM / 32, 8), 256, 0, stream>>>(g, w2e0, w2e1, out);
}

// Round 2
// 645.078 us; speedup vs baseline: 1.0288x; 1.0288x over previous
//
#include <hip/hip_runtime.h>

typedef __bf16 bf16;
typedef __attribute__((ext_vector_type(8))) __bf16 bf16x8;
typedef __attribute__((ext_vector_type(4))) float f32x4;

#define T 128
#define DIM 4096
#define NACT 11468
#define A_PAD 11520   // 360 tiles of 32
#define NCH 8
#define KCH (A_PAD / NCH)   // 1440, 45 K-steps of 32 (odd -> single-step epilogue)

// ---------------- pre-kernel: x fp32 -> bf16 ----------------
__global__ __launch_bounds__(256) void k_cvt_x(const float* __restrict__ x,
                                               bf16* __restrict__ xb) {
  int i = (blockIdx.x * 256 + threadIdx.x) * 8;
  f32x4 a = *(const f32x4*)(x + i);
  f32x4 b = *(const f32x4*)(x + i + 4);
  bf16x8 o;
  o[0] = (bf16)a[0]; o[1] = (bf16)a[1]; o[2] = (bf16)a[2]; o[3] = (bf16)a[3];
  o[4] = (bf16)b[0]; o[5] = (bf16)b[1]; o[6] = (bf16)b[2]; o[7] = (bf16)b[3];
  *(bf16x8*)(xb + i) = o;
}

// ---------------- phase 1: g_e = silu(x w1^T) * (x w3^T) * ew_e ----------------
// block = 256 threads = 4 waves: wave = (wm in {0,1}) x (wn in {0,1})
// wave computes M=64 (rows wm*64..) x N=16 (cols bx*32 + wn*16 ..)
// Depth-2 register pipeline: load stage k+1 while MFMA'ing stage k.
struct P1Stage {
  f32x4 l1a, l1b, l3a, l3b;
  bf16x8 xa0, xa1, xa2, xa3;
};

__global__ __launch_bounds__(256, 2) void k_phase1(
    const bf16* __restrict__ xb,
    const float* __restrict__ w1e0, const float* __restrict__ w3e0,
    const float* __restrict__ w1e1, const float* __restrict__ w3e1,
    const float* __restrict__ ew, const int* __restrict__ ids,
    bf16* __restrict__ gws) {
  const int e = blockIdx.y;
  const float* __restrict__ w1 = e ? w1e1 : w1e0;
  const float* __restrict__ w3 = e ? w3e1 : w3e0;
  bf16* __restrict__ g = gws + (size_t)e * T * A_PAD;

  const int tid = threadIdx.x;
  const int wave = tid >> 6;
  const int lane = tid & 63;
  const int ln = lane & 15;     // fragment row index (a for B, t for A)
  const int kh = lane >> 4;     // k-half group (0..3), 8 elems each
  const int wm = wave >> 1;     // m half
  const int wn = wave & 1;      // n 16-group

  const int arow = blockIdx.x * 32 + wn * 16 + ln;
  const int arow_c = arow < NACT ? arow : NACT - 1;  // clamp loads, mask stores

  const float* __restrict__ p1 = w1 + (size_t)arow_c * DIM + kh * 8;
  const float* __restrict__ p3 = w3 + (size_t)arow_c * DIM + kh * 8;
  const bf16* __restrict__ px = xb + (size_t)(wm * 64 + ln) * DIM + kh * 8;

  f32x4 accu0 = {0,0,0,0}, accu1 = {0,0,0,0}, accu2 = {0,0,0,0}, accu3 = {0,0,0,0};
  f32x4 accg0 = {0,0,0,0}, accg1 = {0,0,0,0}, accg2 = {0,0,0,0}, accg3 = {0,0,0,0};

#define P1_LOAD(S, K0) do {                                                  \
    S.l1a = *(const f32x4*)(p1 + (K0));                                      \
    S.l1b = *(const f32x4*)(p1 + (K0) + 4);                                  \
    S.l3a = *(const f32x4*)(p3 + (K0));                                      \
    S.l3b = *(const f32x4*)(p3 + (K0) + 4);                                  \
    S.xa0 = *(const bf16x8*)(px + (K0));                                     \
    S.xa1 = *(const bf16x8*)(px + (size_t)16 * DIM + (K0));                  \
    S.xa2 = *(const bf16x8*)(px + (size_t)32 * DIM + (K0));                  \
    S.xa3 = *(const bf16x8*)(px + (size_t)48 * DIM + (K0));                  \
  } while (0)

#define P1_COMP(S) do {                                                      \
    bf16x8 f1, f3;                                                           \
    f1[0] = (bf16)S.l1a[0]; f1[1] = (bf16)S.l1a[1];                          \
    f1[2] = (bf16)S.l1a[2]; f1[3] = (bf16)S.l1a[3];                          \
    f1[4] = (bf16)S.l1b[0]; f1[5] = (bf16)S.l1b[1];                          \
    f1[6] = (bf16)S.l1b[2]; f1[7] = (bf16)S.l1b[3];                          \
    f3[0] = (bf16)S.l3a[0]; f3[1] = (bf16)S.l3a[1];                          \
    f3[2] = (bf16)S.l3a[2]; f3[3] = (bf16)S.l3a[3];                          \
    f3[4] = (bf16)S.l3b[0]; f3[5] = (bf16)S.l3b[1];                          \
    f3[6] = (bf16)S.l3b[2]; f3[7] = (bf16)S.l3b[3];                          \
    accu0 = __builtin_amdgcn_mfma_f32_16x16x32_bf16(S.xa0, f3, accu0, 0, 0, 0); \
    accg0 = __builtin_amdgcn_mfma_f32_16x16x32_bf16(S.xa0, f1, accg0, 0, 0, 0); \
    accu1 = __builtin_amdgcn_mfma_f32_16x16x32_bf16(S.xa1, f3, accu1, 0, 0, 0); \
    accg1 = __builtin_amdgcn_mfma_f32_16x16x32_bf16(S.xa1, f1, accg1, 0, 0, 0); \
    accu2 = __builtin_amdgcn_mfma_f32_16x16x32_bf16(S.xa2, f3, accu2, 0, 0, 0); \
    accg2 = __builtin_amdgcn_mfma_f32_16x16x32_bf16(S.xa2, f1, accg2, 0, 0, 0); \
    accu3 = __builtin_amdgcn_mfma_f32_16x16x32_bf16(S.xa3, f3, accu3, 0, 0, 0); \
    accg3 = __builtin_amdgcn_mfma_f32_16x16x32_bf16(S.xa3, f1, accg3, 0, 0, 0); \
  } while (0)

  P1Stage s0, s1;
  P1_LOAD(s0, 0);
  for (int k0 = 0; k0 < DIM - 64; k0 += 64) {
    P1_LOAD(s1, k0 + 32);
    P1_COMP(s0);
    P1_LOAD(s0, k0 + 64);
    P1_COMP(s1);
  }
  P1_LOAD(s1, DIM - 32);
  P1_COMP(s0);
  P1_COMP(s1);

  // routing weights (swap if incoming expert_ids[0] != 0)
  float e0 = ew[0], e1 = ew[1];
  if (ids[0] != 0) { float t = e0; e0 = e1; e1 = t; }
  const float sel = e ? e1 : e0;
  const bool valid = arow < NACT;

  f32x4 au[4] = {accu0, accu1, accu2, accu3};
  f32x4 ag[4] = {accg0, accg1, accg2, accg3};
#pragma unroll
  for (int m = 0; m < 4; ++m) {
#pragma unroll
    for (int j = 0; j < 4; ++j) {
      int t = wm * 64 + m * 16 + kh * 4 + j;  // C/D: row=(lane>>4)*4+reg, col=lane&15
      float up = au[m][j];
      float gt = ag[m][j];
      float sg = gt / (1.f + __expf(-gt));
      float val = valid ? sg * up * sel : 0.f;
      g[(size_t)t * A_PAD + arow] = (bf16)val;
    }
  }
#undef P1_LOAD
#undef P1_COMP
}

// ---------------- phase 2: out += sum_e g_e @ w2_e  (split-K, atomic fp32) ----------------
// block = 256 = 4 waves (wm x wn); wave: M=64 x N=16; grid (DIM/32, 2 experts * 8 kchunks)
struct P2Stage {
  bf16x8 g0, g1, g2, g3;
  float w0, w1, w2, w3, w4, w5, w6, w7;
};

__global__ __launch_bounds__(256, 2) void k_phase2(
    const bf16* __restrict__ gws,
    const float* __restrict__ w2e0, const float* __restrict__ w2e1,
    float* __restrict__ out) {
  const int e = blockIdx.y >> 3;
  const int kc = blockIdx.y & 7;
  const float* __restrict__ w2 = e ? w2e1 : w2e0;
  const bf16* __restrict__ g = gws + (size_t)e * T * A_PAD;

  const int tid = threadIdx.x;
  const int wave = tid >> 6;
  const int lane = tid & 63;
  const int ln = lane & 15;
  const int kh = lane >> 4;
  const int wm = wave >> 1;
  const int wn = wave & 1;

  const int dcol = blockIdx.x * 32 + wn * 16 + ln;
  const int kbase = kc * KCH;
  const bool chunk_safe = (kbase + KCH) <= NACT;  // only last chunk needs clamping

  f32x4 acc0 = {0,0,0,0}, acc1 = {0,0,0,0}, acc2 = {0,0,0,0}, acc3 = {0,0,0,0};

  const bf16* __restrict__ pg = g + (size_t)(wm * 64 + ln) * A_PAD + kh * 8;
  const float* __restrict__ pw = w2 + dcol;

#define P2_LOAD(S, K0) do {                                                  \
    S.g0 = *(const bf16x8*)(pg + (K0));                                      \
    S.g1 = *(const bf16x8*)(pg + (size_t)16 * A_PAD + (K0));                 \
    S.g2 = *(const bf16x8*)(pg + (size_t)32 * A_PAD + (K0));                 \
    S.g3 = *(const bf16x8*)(pg + (size_t)48 * A_PAD + (K0));                 \
    int kr = (K0) + kh * 8;                                                  \
    if (chunk_safe || kr + 7 < NACT) {                                       \
      const float* p = pw + (size_t)kr * DIM;                                \
      S.w0 = p[0];                 S.w1 = p[(size_t)1 * DIM];                \
      S.w2 = p[(size_t)2 * DIM];   S.w3 = p[(size_t)3 * DIM];                \
      S.w4 = p[(size_t)4 * DIM];   S.w5 = p[(size_t)5 * DIM];                \
      S.w6 = p[(size_t)6 * DIM];   S.w7 = p[(size_t)7 * DIM];                \
    } else {                                                                 \
      int k0c = kr + 0 < NACT ? kr + 0 : NACT - 1;                           \
      int k1c = kr + 1 < NACT ? kr + 1 : NACT - 1;                           \
      int k2c = kr + 2 < NACT ? kr + 2 : NACT - 1;                           \
      int k3c = kr + 3 < NACT ? kr + 3 : NACT - 1;                           \
      int k4c = kr + 4 < NACT ? kr + 4 : NACT - 1;                           \
      int k5c = kr + 5 < NACT ? kr + 5 : NACT - 1;                           \
      int k6c = kr + 6 < NACT ? kr + 6 : NACT - 1;                           \
      int k7c = kr + 7 < NACT ? kr + 7 : NACT - 1;                           \
      S.w0 = pw[(size_t)k0c * DIM]; S.w1 = pw[(size_t)k1c * DIM];            \
      S.w2 = pw[(size_t)k2c * DIM]; S.w3 = pw[(size_t)k3c * DIM];            \
      S.w4 = pw[(size_t)k4c * DIM]; S.w5 = pw[(size_t)k5c * DIM];            \
      S.w6 = pw[(size_t)k6c * DIM]; S.w7 = pw[(size_t)k7c * DIM];            \
    }                                                                        \
  } while (0)

#define P2_COMP(S) do {                                                      \
    bf16x8 bw;                                                               \
    bw[0] = (bf16)S.w0; bw[1] = (bf16)S.w1; bw[2] = (bf16)S.w2;              \
    bw[3] = (bf16)S.w3; bw[4] = (bf16)S.w4; bw[5] = (bf16)S.w5;              \
    bw[6] = (bf16)S.w6; bw[7] = (bf16)S.w7;                                  \
    acc0 = __builtin_amdgcn_mfma_f32_16x16x32_bf16(S.g0, bw, acc0, 0, 0, 0); \
    acc1 = __builtin_amdgcn_mfma_f32_16x16x32_bf16(S.g1, bw, acc1, 0, 0, 0); \
    acc2 = __builtin_amdgcn_mfma_f32_16x16x32_bf16(S.g2, bw, acc2, 0, 0, 0); \
    acc3 = __builtin_amdgcn_mfma_f32_16x16x32_bf16(S.g3, bw, acc3, 0, 0, 0); \
  } while (0)

  P2Stage s0, s1;
  P2_LOAD(s0, kbase);
  int k0 = kbase;
  for (; k0 + 64 < kbase + KCH; k0 += 64) {
    P2_LOAD(s1, k0 + 32);
    P2_COMP(s0);
    P2_LOAD(s0, k0 + 64);
    P2_COMP(s1);
  }
  P2_COMP(s0);  // KCH/32 = 45 is odd: exactly one stage left

  f32x4 ac[4] = {acc0, acc1, acc2, acc3};
#pragma unroll
  for (int m = 0; m < 4; ++m) {
#pragma unroll
    for (int j = 0; j < 4; ++j) {
      int t = wm * 64 + m * 16 + kh * 4 + j;
      atomicAdd(out + (size_t)t * DIM + dcol, ac[m][j]);
    }
  }
#undef P2_LOAD
#undef P2_COMP
}

// ---------------- launch ----------------
extern "C" void kernel_launch(void* const* d_in, const int* in_sizes, int n_in,
                              void* d_out, int out_size, void* d_ws, size_t ws_size,
                              hipStream_t stream) {
  const float* x    = (const float*)d_in[0];
  const float* ew   = (const float*)d_in[1];
  const int*   ids  = (const int*)d_in[2];
  const float* w1e0 = (const float*)d_in[3];
  const float* w3e0 = (const float*)d_in[4];
  const float* w2e0 = (const float*)d_in[5];
  const float* w1e1 = (const float*)d_in[6];
  const float* w3e1 = (const float*)d_in[7];
  const float* w2e1 = (const float*)d_in[8];
  float* out = (float*)d_out;

  bf16* xb = (bf16*)d_ws;                                   // 128*4096*2 = 1 MB
  bf16* g  = (bf16*)((char*)d_ws + (size_t)T * DIM * 2);    // 2 * 128*11520*2 = 5.9 MB

  hipMemsetAsync(d_out, 0, (size_t)T * DIM * sizeof(float), stream);
  k_cvt_x<<<dim3((T * DIM) / (256 * 8)), 256, 0, stream>>>(x, xb);
  k_phase1<<<dim3(A_PAD / 32, 2), 256, 0, stream>>>(xb, w1e0, w3e0, w1e1, w3e1, ew, ids, g);
  k_phase2<<<dim3(DIM / 32, 16), 256, 0, stream>>>(g, w2e0, w2e1, out);
}

// Round 3
// 444.026 us; speedup vs baseline: 1.4947x; 1.4528x over previous
//
#include <hip/hip_runtime.h>

typedef __bf16 bf16;
typedef __attribute__((ext_vector_type(8))) __bf16 bf16x8;
typedef __attribute__((ext_vector_type(4))) float f32x4;

#define T 128
#define DIM 4096
#define NACT 11468
#define A_PAD 11520   // 360 tiles of 32
#define NCH 4
#define KCH (A_PAD / NCH)   // 2880 -> 45 chunks of 64
#define NC2 (KCH / 64)      // 45

#define GLOAD16(src, dst)                                                          \
  __builtin_amdgcn_global_load_lds(                                                \
      (__attribute__((address_space(1))) const void*)(src),                        \
      (__attribute__((address_space(3))) void*)(dst), 16, 0, 0)

// ---------------- pre-kernel: x fp32 -> bf16 ----------------
__global__ __launch_bounds__(256) void k_cvt_x(const float* __restrict__ x,
                                               bf16* __restrict__ xb) {
  int i = (blockIdx.x * 256 + threadIdx.x) * 8;
  f32x4 a = *(const f32x4*)(x + i);
  f32x4 b = *(const f32x4*)(x + i + 4);
  bf16x8 o;
  o[0] = (bf16)a[0]; o[1] = (bf16)a[1]; o[2] = (bf16)a[2]; o[3] = (bf16)a[3];
  o[4] = (bf16)b[0]; o[5] = (bf16)b[1]; o[6] = (bf16)b[2]; o[7] = (bf16)b[3];
  *(bf16x8*)(xb + i) = o;
}

// ---------------- phase 1: g_e = silu(x w1^T) * (x w3^T) * ew_e ----------------
// block 256 = 4 waves (wm x wn); wave tile M=64 x N=16; K staged in LDS, BK=64.
// LDS per buffer: w1[32][64]f32 (8KB, XOR-swizzled) + w3 (8KB). Double buffered.
__global__ __launch_bounds__(256, 3) void k_phase1(
    const bf16* __restrict__ xb,
    const float* __restrict__ w1e0, const float* __restrict__ w3e0,
    const float* __restrict__ w1e1, const float* __restrict__ w3e1,
    const float* __restrict__ ew, const int* __restrict__ ids,
    bf16* __restrict__ gws) {
  __shared__ __attribute__((aligned(16))) char smem[32768];
  const int e = blockIdx.y;
  const float* __restrict__ w1 = e ? w1e1 : w1e0;
  const float* __restrict__ w3 = e ? w3e1 : w3e0;
  bf16* __restrict__ g = gws + (size_t)e * T * A_PAD;

  const int tid = threadIdx.x;
  const int wv = tid >> 6;
  const int lane = tid & 63;
  const int ln = lane & 15;
  const int kh = lane >> 4;       // == lane>>4, used as staging sub-row too
  const int wm = wv >> 1;
  const int wn = wv & 1;
  const int bx32 = blockIdx.x * 32;

  // Staging: 16 x 1KB instrs/chunk, 4 per wave. gi=wv*4+i; gi<8 -> w1 rows, else w3.
  // instr covers rows (gi&7)*4 .. +3 (lane>>4 picks row), 64 floats/row.
  // Source pre-swizzled so that LDS-linear layout equals swizzled tile (rule #21).
  const char* sbase[4];
  char* sdst[4];
#pragma unroll
  for (int i = 0; i < 4; ++i) {
    const int gi = wv * 4 + i;
    const float* wp = (gi < 8) ? w1 : w3;
    const int row = ((gi & 7) << 2) + kh;
    int grow = bx32 + row;
    grow = grow < NACT ? grow : NACT - 1;
    const int kbyte = ((lane & 15) << 4) ^ ((row & 7) << 4);  // pre-swizzled source
    sbase[i] = (const char*)wp + ((size_t)grow * DIM) * 4 + kbyte;
    sdst[i] = smem + gi * 1024;
  }

  const bf16* __restrict__ px = xb + (size_t)(wm * 64 + ln) * DIM + kh * 8;
  const int wrow = wn * 16 + ln;
  const int swz = (wrow & 7) << 4;

  f32x4 accu[4], accg[4];
#pragma unroll
  for (int m = 0; m < 4; ++m) {
    accu[m] = (f32x4){0.f, 0.f, 0.f, 0.f};
    accg[m] = (f32x4){0.f, 0.f, 0.f, 0.f};
  }

  // prologue: stage chunk 0 into buf 0
#pragma unroll
  for (int i = 0; i < 4; ++i) GLOAD16(sbase[i], sdst[i]);

  for (int c = 0; c < DIM / 64; ++c) {
    const int cur = c & 1;
    __syncthreads();  // staging(cur) complete; prior reads of other buf done
    if (c + 1 < DIM / 64) {
      const size_t koff = (size_t)(c + 1) * 256;  // 64 floats * 4B
      char* const db = smem + (((c + 1) & 1) << 14);
#pragma unroll
      for (int i = 0; i < 4; ++i) GLOAD16(sbase[i] + koff, db + (wv * 4 + i) * 1024);
    }

    const char* b1 = smem + (cur << 14) + wrow * 256;
    const char* b3 = b1 + 8192;
    const bf16* pxc = px + c * 64;

    bf16x8 xf[2][4];
#pragma unroll
    for (int ks = 0; ks < 2; ++ks)
#pragma unroll
      for (int m = 0; m < 4; ++m)
        xf[ks][m] = *(const bf16x8*)(pxc + (size_t)m * 16 * DIM + ks * 32);

#pragma unroll
    for (int ks = 0; ks < 2; ++ks) {
      f32x4 u0 = *(const f32x4*)(b1 + ((ks * 128 + kh * 32) ^ swz));
      f32x4 u1 = *(const f32x4*)(b1 + ((ks * 128 + kh * 32 + 16) ^ swz));
      f32x4 v0 = *(const f32x4*)(b3 + ((ks * 128 + kh * 32) ^ swz));
      f32x4 v1 = *(const f32x4*)(b3 + ((ks * 128 + kh * 32 + 16) ^ swz));
      bf16x8 f1, f3;
      f1[0] = (bf16)u0[0]; f1[1] = (bf16)u0[1]; f1[2] = (bf16)u0[2]; f1[3] = (bf16)u0[3];
      f1[4] = (bf16)u1[0]; f1[5] = (bf16)u1[1]; f1[6] = (bf16)u1[2]; f1[7] = (bf16)u1[3];
      f3[0] = (bf16)v0[0]; f3[1] = (bf16)v0[1]; f3[2] = (bf16)v0[2]; f3[3] = (bf16)v0[3];
      f3[4] = (bf16)v1[0]; f3[5] = (bf16)v1[1]; f3[6] = (bf16)v1[2]; f3[7] = (bf16)v1[3];
#pragma unroll
      for (int m = 0; m < 4; ++m) {
        accu[m] = __builtin_amdgcn_mfma_f32_16x16x32_bf16(xf[ks][m], f3, accu[m], 0, 0, 0);
        accg[m] = __builtin_amdgcn_mfma_f32_16x16x32_bf16(xf[ks][m], f1, accg[m], 0, 0, 0);
      }
    }
  }

  // routing weights (swap if incoming expert_ids[0] != 0)
  float e0 = ew[0], e1 = ew[1];
  if (ids[0] != 0) { float t = e0; e0 = e1; e1 = t; }
  const float sel = e ? e1 : e0;
  const int arow = bx32 + wrow;
  const bool valid = arow < NACT;

#pragma unroll
  for (int m = 0; m < 4; ++m) {
#pragma unroll
    for (int j = 0; j < 4; ++j) {
      int t = wm * 64 + m * 16 + kh * 4 + j;  // C/D: row=(lane>>4)*4+reg, col=lane&15
      float up = accu[m][j];
      float gt = accg[m][j];
      float sg = gt / (1.f + __expf(-gt));
      float val = valid ? sg * up * sel : 0.f;
      g[(size_t)t * A_PAD + arow] = (bf16)val;
    }
  }
}

// ---------------- phase 2: out += sum_e g_e @ w2_e  (split-K, atomic fp32) ----------------
// block 256 = 4 waves; wave M=64 x N=16. w2 [64k][32d] f32 staged in LDS (8KB x2);
// g loaded direct (L2/L3-resident, kh-lanes coalesce to 64B lines).
__global__ __launch_bounds__(256, 4) void k_phase2(
    const bf16* __restrict__ gws,
    const float* __restrict__ w2e0, const float* __restrict__ w2e1,
    float* __restrict__ out) {
  __shared__ __attribute__((aligned(16))) char smem[16384];
  const int e = blockIdx.y >> 2;
  const int kc = blockIdx.y & 3;
  const float* __restrict__ w2 = e ? w2e1 : w2e0;
  const bf16* __restrict__ g = gws + (size_t)e * T * A_PAD;

  const int tid = threadIdx.x;
  const int wv = tid >> 6;
  const int lane = tid & 63;
  const int ln = lane & 15;
  const int kh = lane >> 4;
  const int wm = wv >> 1;
  const int wn = wv & 1;
  const int bx32 = blockIdx.x * 32;
  const int kcbase = kc * KCH;

  // Staging: 8 x 1KB instrs/chunk, 2 per wave. gi=wv*2+i covers k-rows gi*8..+7,
  // 32 floats (128B) of d per row: lane covers (krow = gi*8 + lane/8, dbyte=(lane&7)*16).
  const char* sbase[2];
  char* sdst[2];
  int srow[2];
#pragma unroll
  for (int i = 0; i < 2; ++i) {
    const int gi = wv * 2 + i;
    const int krow = (gi << 3) + (lane >> 3);
    srow[i] = krow;
    sbase[i] = (const char*)w2 + ((size_t)krow * DIM + bx32) * 4 + ((lane & 7) << 4);
    sdst[i] = smem + gi * 1024;
  }

  const bf16* __restrict__ pg = g + (size_t)(wm * 64 + ln) * A_PAD + kh * 8 + kcbase;
  const int dl = wn * 16 + ln;  // d within tile

  f32x4 acc[4];
#pragma unroll
  for (int m = 0; m < 4; ++m) acc[m] = (f32x4){0.f, 0.f, 0.f, 0.f};

#define STAGE2(c_, db_) do {                                                       \
    const int kb_ = kcbase + (c_) * 64;                                            \
    if (kb_ + 63 < NACT) {                                                         \
      const size_t off_ = (size_t)kb_ * DIM * 4;                                   \
      _Pragma("unroll")                                                            \
      for (int i = 0; i < 2; ++i) GLOAD16(sbase[i] + off_, (db_) + (wv * 2 + i) * 1024); \
    } else {                                                                       \
      _Pragma("unroll")                                                            \
      for (int i = 0; i < 2; ++i) {                                                \
        int kg_ = kb_ + srow[i];                                                   \
        kg_ = kg_ < NACT ? kg_ : NACT - 1;                                         \
        const char* s_ = (const char*)w2 + ((size_t)kg_ * DIM + bx32) * 4 + ((lane & 7) << 4); \
        GLOAD16(s_, (db_) + (wv * 2 + i) * 1024);                                  \
      }                                                                            \
    }                                                                              \
  } while (0)

  STAGE2(0, smem);

  for (int c = 0; c < NC2; ++c) {
    const int cur = c & 1;
    __syncthreads();
    if (c + 1 < NC2) STAGE2(c + 1, smem + (((c + 1) & 1) << 13));

    const bf16* pgc = pg + c * 64;
    bf16x8 gf[2][4];
#pragma unroll
    for (int ks = 0; ks < 2; ++ks)
#pragma unroll
      for (int m = 0; m < 4; ++m)
        gf[ks][m] = *(const bf16x8*)(pgc + (size_t)m * 16 * A_PAD + ks * 32);

    const char* bw = smem + (cur << 13) + dl * 4;
#pragma unroll
    for (int ks = 0; ks < 2; ++ks) {
      bf16x8 wf;
#pragma unroll
      for (int j = 0; j < 8; ++j)
        wf[j] = (bf16)(*(const float*)(bw + (ks * 32 + kh * 8 + j) * 128));
#pragma unroll
      for (int m = 0; m < 4; ++m)
        acc[m] = __builtin_amdgcn_mfma_f32_16x16x32_bf16(gf[ks][m], wf, acc[m], 0, 0, 0);
    }
  }
#undef STAGE2

  const int dcol = bx32 + dl;
#pragma unroll
  for (int m = 0; m < 4; ++m) {
#pragma unroll
    for (int j = 0; j < 4; ++j) {
      int t = wm * 64 + m * 16 + kh * 4 + j;
      atomicAdd(out + (size_t)t * DIM + dcol, acc[m][j]);
    }
  }
}

// ---------------- launch ----------------
extern "C" void kernel_launch(void* const* d_in, const int* in_sizes, int n_in,
                              void* d_out, int out_size, void* d_ws, size_t ws_size,
                              hipStream_t stream) {
  const float* x    = (const float*)d_in[0];
  const float* ew   = (const float*)d_in[1];
  const int*   ids  = (const int*)d_in[2];
  const float* w1e0 = (const float*)d_in[3];
  const float* w3e0 = (const float*)d_in[4];
  const float* w2e0 = (const float*)d_in[5];
  const float* w1e1 = (const float*)d_in[6];
  const float* w3e1 = (const float*)d_in[7];
  const float* w2e1 = (const float*)d_in[8];
  float* out = (float*)d_out;

  bf16* xb = (bf16*)d_ws;                                   // 128*4096*2 = 1 MB
  bf16* g  = (bf16*)((char*)d_ws + (size_t)T * DIM * 2);    // 2 * 128*11520*2 = 5.9 MB

  hipMemsetAsync(d_out, 0, (size_t)T * DIM * sizeof(float), stream);
  k_cvt_x<<<dim3((T * DIM) / (256 * 8)), 256, 0, stream>>>(x, xb);
  k_phase1<<<dim3(A_PAD / 32, 2), 256, 0, stream>>>(xb, w1e0, w3e0, w1e1, w3e1, ew, ids, g);
  k_phase2<<<dim3(DIM / 32, 2 * NCH), 256, 0, stream>>>(g, w2e0, w2e1, out);
}

// Round 4
// 428.629 us; speedup vs baseline: 1.5484x; 1.0359x over previous
//
#include <hip/hip_runtime.h>

typedef __bf16 bf16;
typedef __attribute__((ext_vector_type(8))) __bf16 bf16x8;
typedef __attribute__((ext_vector_type(4))) float f32x4;

#define T 128
#define DIM 4096
#define NACT 11468
#define A_PAD 11520   // 360 tiles of 32
#define NCH 6
#define KCH (A_PAD / NCH)   // 1920 -> 30 chunks of 64
#define NC2 (KCH / 64)      // 30 (even)

#define GLOAD16(src, dst)                                                          \
  __builtin_amdgcn_global_load_lds(                                                \
      (__attribute__((address_space(1))) const void*)(src),                        \
      (__attribute__((address_space(3))) void*)(dst), 16, 0, 0)

#define WAITCNT(n) asm volatile("s_waitcnt vmcnt(" #n ")" ::: "memory")
#define BAR() __builtin_amdgcn_s_barrier()

// ---------------- pre-kernel: x fp32 -> bf16 ----------------
__global__ __launch_bounds__(256) void k_cvt_x(const float* __restrict__ x,
                                               bf16* __restrict__ xb) {
  int i = (blockIdx.x * 256 + threadIdx.x) * 8;
  f32x4 a = *(const f32x4*)(x + i);
  f32x4 b = *(const f32x4*)(x + i + 4);
  bf16x8 o;
  o[0] = (bf16)a[0]; o[1] = (bf16)a[1]; o[2] = (bf16)a[2]; o[3] = (bf16)a[3];
  o[4] = (bf16)b[0]; o[5] = (bf16)b[1]; o[6] = (bf16)b[2]; o[7] = (bf16)b[3];
  *(bf16x8*)(xb + i) = o;
}

// ---------------- phase 1: g_e = silu(x w1^T) * (x w3^T) * ew_e ----------------
// 4 waves; wave tile M=64 x N=16. 3 LDS buffers x 16KB (w1|w3 [32][64]f32, swizzled),
// depth-2 counted-vmcnt pipeline. Per wave per chunk: 4 stage gloads + 8 x gloads.
__global__ __launch_bounds__(256, 3) void k_phase1(
    const bf16* __restrict__ xb,
    const float* __restrict__ w1e0, const float* __restrict__ w3e0,
    const float* __restrict__ w1e1, const float* __restrict__ w3e1,
    const float* __restrict__ ew, const int* __restrict__ ids,
    bf16* __restrict__ gws) {
  __shared__ __attribute__((aligned(16))) char smem[3 * 16384];
  const int e = blockIdx.y;
  const float* __restrict__ w1 = e ? w1e1 : w1e0;
  const float* __restrict__ w3 = e ? w3e1 : w3e0;
  bf16* __restrict__ g = gws + (size_t)e * T * A_PAD;

  const int tid = threadIdx.x;
  const int wv = tid >> 6;
  const int lane = tid & 63;
  const int ln = lane & 15;
  const int kh = lane >> 4;
  const int wm = wv >> 1;
  const int wn = wv & 1;
  const int bx32 = blockIdx.x * 32;

  // staging sources (pre-swizzled so linear LDS == swizzled tile; rule #21)
  const char* sbase[4];
#pragma unroll
  for (int i = 0; i < 4; ++i) {
    const int gi = wv * 4 + i;
    const float* wp = (gi < 8) ? w1 : w3;
    const int row = ((gi & 7) << 2) + kh;
    int grow = bx32 + row;
    grow = grow < NACT ? grow : NACT - 1;
    const int kbyte = ((lane & 15) << 4) ^ ((row & 7) << 4);
    sbase[i] = (const char*)wp + ((size_t)grow * DIM) * 4 + kbyte;
  }

  const bf16* __restrict__ px = xb + (size_t)(wm * 64 + ln) * DIM + kh * 8;
  const int wrow = wn * 16 + ln;
  const int swz = (wrow & 7) << 4;

  f32x4 accu[4], accg[4];
#pragma unroll
  for (int m = 0; m < 4; ++m) {
    accu[m] = (f32x4){0.f, 0.f, 0.f, 0.f};
    accg[m] = (f32x4){0.f, 0.f, 0.f, 0.f};
  }

  auto STAGE = [&](int c) {
    const size_t koff = (size_t)c * 256;
    char* db = smem + (c % 3) * 16384;
#pragma unroll
    for (int i = 0; i < 4; ++i) GLOAD16(sbase[i] + koff, db + (wv * 4 + i) * 1024);
  };
  auto XLOAD = [&](bf16x8 (&xf)[8], int c) {
    const bf16* p_ = px + (size_t)c * 64;
#pragma unroll
    for (int ks = 0; ks < 2; ++ks)
#pragma unroll
      for (int m = 0; m < 4; ++m)
        xf[ks * 4 + m] = *(const bf16x8*)(p_ + (size_t)m * 16 * DIM + ks * 32);
  };
  auto COMP = [&](const bf16x8 (&xf)[8], int c) {
    const char* b1 = smem + (c % 3) * 16384 + wrow * 256;
    const char* b3 = b1 + 8192;
#pragma unroll
    for (int ks = 0; ks < 2; ++ks) {
      f32x4 u0 = *(const f32x4*)(b1 + ((ks * 128 + kh * 32) ^ swz));
      f32x4 u1 = *(const f32x4*)(b1 + ((ks * 128 + kh * 32 + 16) ^ swz));
      f32x4 v0 = *(const f32x4*)(b3 + ((ks * 128 + kh * 32) ^ swz));
      f32x4 v1 = *(const f32x4*)(b3 + ((ks * 128 + kh * 32 + 16) ^ swz));
      bf16x8 f1, f3;
      f1[0] = (bf16)u0[0]; f1[1] = (bf16)u0[1]; f1[2] = (bf16)u0[2]; f1[3] = (bf16)u0[3];
      f1[4] = (bf16)u1[0]; f1[5] = (bf16)u1[1]; f1[6] = (bf16)u1[2]; f1[7] = (bf16)u1[3];
      f3[0] = (bf16)v0[0]; f3[1] = (bf16)v0[1]; f3[2] = (bf16)v0[2]; f3[3] = (bf16)v0[3];
      f3[4] = (bf16)v1[0]; f3[5] = (bf16)v1[1]; f3[6] = (bf16)v1[2]; f3[7] = (bf16)v1[3];
#pragma unroll
      for (int m = 0; m < 4; ++m) {
        accu[m] = __builtin_amdgcn_mfma_f32_16x16x32_bf16(xf[ks * 4 + m], f3, accu[m], 0, 0, 0);
        accg[m] = __builtin_amdgcn_mfma_f32_16x16x32_bf16(xf[ks * 4 + m], f1, accg[m], 0, 0, 0);
      }
    }
  };

  bf16x8 xfA[8], xfB[8];
  // prologue: S0, XA0, S1 in flight (16 loads)
  STAGE(0);
  XLOAD(xfA, 0);
  STAGE(1);

  for (int c = 0; c < 62; c += 2) {
    XLOAD(xfB, c + 1);          // outstanding: S(c)4 XA(c)8 S(c+1)4 XB(c+1)8 = 24
    WAITCNT(12);                // retire S(c), XA(c)
    BAR();
    STAGE(c + 2);
    COMP(xfA, c);
    XLOAD(xfA, c + 2);          // outstanding: S(c+1)4 XB8 S(c+2)4 XA8 = 24
    WAITCNT(12);                // retire S(c+1), XB... wait: retires S(c+1)+XB? no: leaves 12 newest
    BAR();
    STAGE(c + 3);
    COMP(xfB, c + 1);
  }
  // peel chunks 62, 63
  XLOAD(xfB, 63);
  WAITCNT(12);
  BAR();
  COMP(xfA, 62);
  WAITCNT(0);
  BAR();
  COMP(xfB, 63);

  // routing weights (swap if incoming expert_ids[0] != 0)
  float e0 = ew[0], e1 = ew[1];
  if (ids[0] != 0) { float t = e0; e0 = e1; e1 = t; }
  const float sel = e ? e1 : e0;
  const int arow = bx32 + wrow;
  const bool valid = arow < NACT;

#pragma unroll
  for (int m = 0; m < 4; ++m) {
#pragma unroll
    for (int j = 0; j < 4; ++j) {
      int t = wm * 64 + m * 16 + kh * 4 + j;  // C/D: row=(lane>>4)*4+reg, col=lane&15
      float up = accu[m][j];
      float gt = accg[m][j];
      float sg = gt / (1.f + __expf(-gt));
      float val = valid ? sg * up * sel : 0.f;
      g[(size_t)t * A_PAD + arow] = (bf16)val;
    }
  }
}

// ---------------- phase 2: out += sum_e g_e @ w2_e  (split-K, atomic fp32) ----------------
// 4 waves; wave M=64 x N=16. 3 LDS buffers x 8KB (w2 [64k][32d] f32), depth-2
// counted-vmcnt pipeline. Per wave per chunk: 2 stage gloads + 8 g gloads.
__global__ __launch_bounds__(256, 3) void k_phase2(
    const bf16* __restrict__ gws,
    const float* __restrict__ w2e0, const float* __restrict__ w2e1,
    float* __restrict__ out) {
  __shared__ __attribute__((aligned(16))) char smem[3 * 8192];
  const int e = blockIdx.y / NCH;
  const int kc = blockIdx.y % NCH;
  const float* __restrict__ w2 = e ? w2e1 : w2e0;
  const bf16* __restrict__ g = gws + (size_t)e * T * A_PAD;

  const int tid = threadIdx.x;
  const int wv = tid >> 6;
  const int lane = tid & 63;
  const int ln = lane & 15;
  const int kh = lane >> 4;
  const int wm = wv >> 1;
  const int wn = wv & 1;
  const int bx32 = blockIdx.x * 32;
  const int kcbase = kc * KCH;

  const int srowl = (lane >> 3);           // sub-row within 8-row group
  const char* sbase[2];
#pragma unroll
  for (int i = 0; i < 2; ++i) {
    const int gi = wv * 2 + i;
    const int krow = (gi << 3) + srowl;
    sbase[i] = (const char*)w2 + ((size_t)krow * DIM + bx32) * 4 + ((lane & 7) << 4);
  }

  const bf16* __restrict__ pg = g + (size_t)(wm * 64 + ln) * A_PAD + kh * 8 + kcbase;
  const int dl = wn * 16 + ln;

  f32x4 acc[4];
#pragma unroll
  for (int m = 0; m < 4; ++m) acc[m] = (f32x4){0.f, 0.f, 0.f, 0.f};

  auto STAGE2 = [&](int c) {
    const int kb = kcbase + c * 64;
    char* db = smem + (c % 3) * 8192;
    if (kb + 63 < NACT) {
      const size_t off = (size_t)kb * DIM * 4;
#pragma unroll
      for (int i = 0; i < 2; ++i) GLOAD16(sbase[i] + off, db + (wv * 2 + i) * 1024);
    } else {
#pragma unroll
      for (int i = 0; i < 2; ++i) {
        int kg = kb + (((wv * 2 + i) << 3) + srowl);
        kg = kg < NACT ? kg : NACT - 1;   // duplicated rows multiply g==0 in pad
        const char* s_ = (const char*)w2 + ((size_t)kg * DIM + bx32) * 4 + ((lane & 7) << 4);
        GLOAD16(s_, db + (wv * 2 + i) * 1024);
      }
    }
  };
  auto GLOADG = [&](bf16x8 (&gf)[8], int c) {
    const bf16* p_ = pg + (size_t)c * 64;
#pragma unroll
    for (int ks = 0; ks < 2; ++ks)
#pragma unroll
      for (int m = 0; m < 4; ++m)
        gf[ks * 4 + m] = *(const bf16x8*)(p_ + (size_t)m * 16 * A_PAD + ks * 32);
  };
  auto COMP2 = [&](const bf16x8 (&gf)[8], int c) {
    const char* bw = smem + (c % 3) * 8192 + dl * 4;
#pragma unroll
    for (int ks = 0; ks < 2; ++ks) {
      bf16x8 wf;
#pragma unroll
      for (int j = 0; j < 8; ++j)
        wf[j] = (bf16)(*(const float*)(bw + (ks * 32 + kh * 8 + j) * 128));
#pragma unroll
      for (int m = 0; m < 4; ++m)
        acc[m] = __builtin_amdgcn_mfma_f32_16x16x32_bf16(gf[ks * 4 + m], wf, acc[m], 0, 0, 0);
    }
  };

  bf16x8 gfA[8], gfB[8];
  STAGE2(0);
  GLOADG(gfA, 0);
  STAGE2(1);

  for (int c = 0; c < NC2 - 2; c += 2) {
    GLOADG(gfB, c + 1);         // outstanding: S(c)2 GA8 S(c+1)2 GB8 = 20
    WAITCNT(10);
    BAR();
    STAGE2(c + 2);
    COMP2(gfA, c);
    GLOADG(gfA, c + 2);
    WAITCNT(10);
    BAR();
    STAGE2(c + 3);
    COMP2(gfB, c + 1);
  }
  // peel chunks NC2-2, NC2-1
  GLOADG(gfB, NC2 - 1);
  WAITCNT(10);
  BAR();
  COMP2(gfA, NC2 - 2);
  WAITCNT(0);
  BAR();
  COMP2(gfB, NC2 - 1);

  const int dcol = bx32 + dl;
#pragma unroll
  for (int m = 0; m < 4; ++m) {
#pragma unroll
    for (int j = 0; j < 4; ++j) {
      int t = wm * 64 + m * 16 + kh * 4 + j;
      atomicAdd(out + (size_t)t * DIM + dcol, acc[m][j]);
    }
  }
}

// ---------------- launch ----------------
extern "C" void kernel_launch(void* const* d_in, const int* in_sizes, int n_in,
                              void* d_out, int out_size, void* d_ws, size_t ws_size,
                              hipStream_t stream) {
  const float* x    = (const float*)d_in[0];
  const float* ew   = (const float*)d_in[1];
  const int*   ids  = (const int*)d_in[2];
  const float* w1e0 = (const float*)d_in[3];
  const float* w3e0 = (const float*)d_in[4];
  const float* w2e0 = (const float*)d_in[5];
  const float* w1e1 = (const float*)d_in[6];
  const float* w3e1 = (const float*)d_in[7];
  const float* w2e1 = (const float*)d_in[8];
  float* out = (float*)d_out;

  bf16* xb = (bf16*)d_ws;                                   // 128*4096*2 = 1 MB
  bf16* g  = (bf16*)((char*)d_ws + (size_t)T * DIM * 2);    // 2 * 128*11520*2 = 5.9 MB

  hipMemsetAsync(d_out, 0, (size_t)T * DIM * sizeof(float), stream);
  k_cvt_x<<<dim3((T * DIM) / (256 * 8)), 256, 0, stream>>>(x, xb);
  k_phase1<<<dim3(A_PAD / 32, 2), 256, 0, stream>>>(xb, w1e0, w3e0, w1e1, w3e1, ew, ids, g);
  k_phase2<<<dim3(DIM / 32, 2 * NCH), 256, 0, stream>>>(g, w2e0, w2e1, out);
}

// Round 5
// 398.406 us; speedup vs baseline: 1.6658x; 1.0759x over previous
//
#include <hip/hip_runtime.h>

typedef __bf16 bf16;
typedef __attribute__((ext_vector_type(8))) __bf16 bf16x8;
typedef __attribute__((ext_vector_type(4))) float f32x4;

#define T 128
#define DIM 4096
#define NACT 11468
#define A_PAD 11520
#define BK1 512
#define NC1 (DIM / BK1)     // 8 chunks, phase 1
#define NCH 6
#define KCH (A_PAD / NCH)   // 1920
#define NC2 (KCH / 64)      // 30 chunks, phase 2

#define GLOAD16(src, dst)                                                          \
  __builtin_amdgcn_global_load_lds(                                                \
      (__attribute__((address_space(1))) const void*)(src),                        \
      (__attribute__((address_space(3))) void*)(dst), 16, 0, 0)

#define WAITCNT(n) asm volatile("s_waitcnt vmcnt(" #n ")" ::: "memory")
#define BAR() __builtin_amdgcn_s_barrier()

// ---------------- pre-kernel: x fp32 -> bf16 ----------------
__global__ __launch_bounds__(256) void k_cvt_x(const float* __restrict__ x,
                                               bf16* __restrict__ xb) {
  int i = (blockIdx.x * 256 + threadIdx.x) * 8;
  f32x4 a = *(const f32x4*)(x + i);
  f32x4 b = *(const f32x4*)(x + i + 4);
  bf16x8 o;
  o[0] = (bf16)a[0]; o[1] = (bf16)a[1]; o[2] = (bf16)a[2]; o[3] = (bf16)a[3];
  o[4] = (bf16)b[0]; o[5] = (bf16)b[1]; o[6] = (bf16)b[2]; o[7] = (bf16)b[3];
  *(bf16x8*)(xb + i) = o;
}

// ---------------- phase 1: g_e = silu(x w1^T) * (x w3^T) * ew_e ----------------
// Block: 16 a-rows (BN=16) x 128 t. 4 waves, wave = M=32 t x N=16 a.
// K chunk BK=512 -> each weight row visited in 2KB contiguous spans (fat HBM bursts).
// LDS: 2 buffers x 64KB (w1 16x2KB | w3 16x2KB), XOR-swizzled via pre-swizzled source.
// Counted-vmcnt: per wave per chunk 16 stage gload_lds + 32 x loads.
__global__ __launch_bounds__(256, 1) void k_phase1(
    const bf16* __restrict__ xb,
    const float* __restrict__ w1e0, const float* __restrict__ w3e0,
    const float* __restrict__ w1e1, const float* __restrict__ w3e1,
    const float* __restrict__ ew, const int* __restrict__ ids,
    bf16* __restrict__ gws) {
  __shared__ __attribute__((aligned(16))) char smem[2][65536];
  const int e = blockIdx.y;
  const float* __restrict__ w1 = e ? w1e1 : w1e0;
  const float* __restrict__ w3 = e ? w3e1 : w3e0;
  bf16* __restrict__ g = gws + (size_t)e * T * A_PAD;

  const int tid = threadIdx.x;
  const int wv = tid >> 6;
  const int lane = tid & 63;
  const int ln = lane & 15;
  const int kh = lane >> 4;
  const int bx16 = blockIdx.x * 16;

  // wave wv stages 16 of the 64 1KB pieces: wv<2 -> w1 rows 0..15, wv>=2 -> w3
  const char* wp = (const char*)((wv >> 1) ? w3 : w1);
  const int rbase = (wv & 1) * 8;  // rows rbase..rbase+7 (two halves each)

  const bf16* __restrict__ px = xb + (size_t)(wv * 32 + ln) * DIM + kh * 8;
  const int swz = (ln & 7) << 4;

  f32x4 accu[2], accg[2];
  accu[0] = (f32x4){0,0,0,0}; accu[1] = (f32x4){0,0,0,0};
  accg[0] = (f32x4){0,0,0,0}; accg[1] = (f32x4){0,0,0,0};
  bf16x8 xf[2][16];

  auto STAGE = [&](int c, int b) {
    char* db = &smem[b][0] + (size_t)wv * 16384;
    const char* wpc = wp + (size_t)c * 2048;  // chunk k-offset within row
#pragma unroll
    for (int i = 0; i < 16; ++i) {
      const int row = rbase + (i >> 1);
      int grow = bx16 + row;
      grow = grow < NACT ? grow : NACT - 1;
      const char* src = wpc + (size_t)grow * (DIM * 4) + (i & 1) * 1024 +
                        ((lane * 16) ^ ((row & 7) << 4));
      GLOAD16(src, db + i * 1024);
    }
  };
  auto XLOAD = [&](int c) {
    const bf16* p = px + (size_t)c * BK1;
#pragma unroll
    for (int m = 0; m < 2; ++m)
#pragma unroll
      for (int ks = 0; ks < 16; ++ks)
        xf[m][ks] = *(const bf16x8*)(p + (size_t)m * 16 * DIM + ks * 32);
  };
  auto COMP = [&](int b) {
    const char* b1 = &smem[b][0] + (size_t)ln * 2048;
    const char* b3 = b1 + 32768;
#pragma unroll
    for (int ks = 0; ks < 16; ++ks) {
      const int o0 = (ks * 128 + kh * 32) ^ swz;
      const int o1 = (ks * 128 + kh * 32 + 16) ^ swz;
      f32x4 u0 = *(const f32x4*)(b1 + o0);
      f32x4 u1 = *(const f32x4*)(b1 + o1);
      f32x4 v0 = *(const f32x4*)(b3 + o0);
      f32x4 v1 = *(const f32x4*)(b3 + o1);
      bf16x8 f1, f3;
      f1[0] = (bf16)u0[0]; f1[1] = (bf16)u0[1]; f1[2] = (bf16)u0[2]; f1[3] = (bf16)u0[3];
      f1[4] = (bf16)u1[0]; f1[5] = (bf16)u1[1]; f1[6] = (bf16)u1[2]; f1[7] = (bf16)u1[3];
      f3[0] = (bf16)v0[0]; f3[1] = (bf16)v0[1]; f3[2] = (bf16)v0[2]; f3[3] = (bf16)v0[3];
      f3[4] = (bf16)v1[0]; f3[5] = (bf16)v1[1]; f3[6] = (bf16)v1[2]; f3[7] = (bf16)v1[3];
#pragma unroll
      for (int m = 0; m < 2; ++m) {
        accg[m] = __builtin_amdgcn_mfma_f32_16x16x32_bf16(xf[m][ks], f1, accg[m], 0, 0, 0);
        accu[m] = __builtin_amdgcn_mfma_f32_16x16x32_bf16(xf[m][ks], f3, accu[m], 0, 0, 0);
      }
    }
  };

  STAGE(0, 0);
  for (int c = 0; c < NC1; ++c) {
    const int b = c & 1;
    XLOAD(c);          // outstanding: S(c)16 + x32
    WAITCNT(32);       // retire S(c); keep x
    BAR();             // tile(c) ready everywhere; buf b^1 free
    if (c + 1 < NC1) {
      STAGE(c + 1, b ^ 1);  // outstanding: x32 + S(c+1)16
      WAITCNT(16);          // retire x(c); keep S(c+1) in flight across COMP
    } else {
      WAITCNT(0);
    }
    COMP(b);
  }

  // routing weights (swap if incoming expert_ids[0] != 0)
  float e0 = ew[0], e1 = ew[1];
  if (ids[0] != 0) { float t = e0; e0 = e1; e1 = t; }
  const float sel = e ? e1 : e0;
  const int a = bx16 + ln;
  const bool valid = a < NACT;

#pragma unroll
  for (int m = 0; m < 2; ++m) {
#pragma unroll
    for (int j = 0; j < 4; ++j) {
      const int t = wv * 32 + m * 16 + kh * 4 + j;  // C/D: row=(lane>>4)*4+j, col=lane&15
      float up = accu[m][j];
      float gt = accg[m][j];
      float sg = gt / (1.f + __expf(-gt));
      float val = valid ? sg * up * sel : 0.f;
      g[(size_t)t * A_PAD + a] = (bf16)val;
    }
  }
}

// ---------------- phase 2: out += sum_e g_e @ w2_e  (split-K, atomic fp32) ----------------
// Block: 128 t x 128 d. 4 waves, wave = M=32 t x N=128 d. Chunk = 64 k-rows,
// each w2 row visited in 512B contiguous spans. LDS: 2 x 32KB [64k][128d] f32.
// Counted-vmcnt: per wave per chunk 8 stage gload_lds + 4 g loads.
__global__ __launch_bounds__(256, 2) void k_phase2(
    const bf16* __restrict__ gws,
    const float* __restrict__ w2e0, const float* __restrict__ w2e1,
    float* __restrict__ out) {
  __shared__ __attribute__((aligned(16))) char smem[2][32768];
  const int e = blockIdx.y / NCH;
  const int kc = blockIdx.y % NCH;
  const float* __restrict__ w2 = e ? w2e1 : w2e0;
  const bf16* __restrict__ g = gws + (size_t)e * T * A_PAD;

  const int tid = threadIdx.x;
  const int wv = tid >> 6;
  const int lane = tid & 63;
  const int ln = lane & 15;
  const int kh = lane >> 4;
  const int bx128 = blockIdx.x * 128;
  const int kcbase = kc * KCH;

  const bf16* __restrict__ pg = g + (size_t)(wv * 32 + ln) * A_PAD + kh * 8 + kcbase;

  f32x4 acc[2][8];
#pragma unroll
  for (int m = 0; m < 2; ++m)
#pragma unroll
    for (int n = 0; n < 8; ++n) acc[m][n] = (f32x4){0, 0, 0, 0};
  bf16x8 gf[2][2];

  auto STAGE2 = [&](int c, int b) {
    char* db = &smem[b][0] + (size_t)wv * 8192;
    const int kb = kcbase + c * 64;
#pragma unroll
    for (int i = 0; i < 8; ++i) {
      int kr = kb + (wv * 8 + i) * 2 + (lane >> 5);
      kr = kr < NACT ? kr : NACT - 1;  // dup row x g==0 pad -> 0 contribution
      const char* src = (const char*)w2 + ((size_t)kr * DIM + bx128) * 4 + (lane & 31) * 16;
      GLOAD16(src, db + i * 1024);
    }
  };
  auto GLOADG = [&](int c) {
    const bf16* p = pg + (size_t)c * 64;
#pragma unroll
    for (int m = 0; m < 2; ++m)
#pragma unroll
      for (int ks = 0; ks < 2; ++ks)
        gf[m][ks] = *(const bf16x8*)(p + (size_t)m * 16 * A_PAD + ks * 32);
  };
  auto COMP2 = [&](int b) {
    const char* base = &smem[b][0];
#pragma unroll
    for (int ks = 0; ks < 2; ++ks)
#pragma unroll
      for (int n = 0; n < 8; ++n) {
        bf16x8 wf;
#pragma unroll
        for (int j = 0; j < 8; ++j) {
          float f = *(const float*)(base + (ks * 32 + kh * 8 + j) * 512 + (n * 16 + ln) * 4);
          wf[j] = (bf16)f;
        }
#pragma unroll
        for (int m = 0; m < 2; ++m)
          acc[m][n] = __builtin_amdgcn_mfma_f32_16x16x32_bf16(gf[m][ks], wf, acc[m][n], 0, 0, 0);
      }
  };

  STAGE2(0, 0);
  for (int c = 0; c < NC2; ++c) {
    const int b = c & 1;
    GLOADG(c);         // outstanding: S(c)8 + g4
    WAITCNT(4);        // retire S(c); keep g
    BAR();
    if (c + 1 < NC2) {
      STAGE2(c + 1, b ^ 1);  // outstanding: g4 + S(c+1)8
      WAITCNT(8);            // retire g(c); keep S(c+1)
    } else {
      WAITCNT(0);
    }
    COMP2(b);
  }

  const int dbase = bx128 + ln;
#pragma unroll
  for (int m = 0; m < 2; ++m) {
#pragma unroll
    for (int n = 0; n < 8; ++n) {
#pragma unroll
      for (int j = 0; j < 4; ++j) {
        const int t = wv * 32 + m * 16 + kh * 4 + j;
        atomicAdd(out + (size_t)t * DIM + dbase + n * 16, acc[m][n][j]);
      }
    }
  }
}

// ---------------- launch ----------------
extern "C" void kernel_launch(void* const* d_in, const int* in_sizes, int n_in,
                              void* d_out, int out_size, void* d_ws, size_t ws_size,
                              hipStream_t stream) {
  const float* x    = (const float*)d_in[0];
  const float* ew   = (const float*)d_in[1];
  const int*   ids  = (const int*)d_in[2];
  const float* w1e0 = (const float*)d_in[3];
  const float* w3e0 = (const float*)d_in[4];
  const float* w2e0 = (const float*)d_in[5];
  const float* w1e1 = (const float*)d_in[6];
  const float* w3e1 = (const float*)d_in[7];
  const float* w2e1 = (const float*)d_in[8];
  float* out = (float*)d_out;

  bf16* xb = (bf16*)d_ws;                                   // 128*4096*2 = 1 MB
  bf16* g  = (bf16*)((char*)d_ws + (size_t)T * DIM * 2);    // 2 * 128*11520*2 = 5.9 MB

  hipMemsetAsync(d_out, 0, (size_t)T * DIM * sizeof(float), stream);
  k_cvt_x<<<dim3((T * DIM) / (256 * 8)), 256, 0, stream>>>(x, xb);
  k_phase1<<<dim3(A_PAD / 16, 2), 256, 0, stream>>>(xb, w1e0, w3e0, w1e1, w3e1, ew, ids, g);
  k_phase2<<<dim3(DIM / 128, 2 * NCH), 256, 0, stream>>>(g, w2e0, w2e1, out);
}

// Round 6
// 341.969 us; speedup vs baseline: 1.9407x; 1.1650x over previous
//
#include <hip/hip_runtime.h>

typedef __bf16 bf16;
typedef __attribute__((ext_vector_type(8))) __bf16 bf16x8;
typedef __attribute__((ext_vector_type(4))) float f32x4;

#define T 128
#define DIM 4096
#define NACT 11468
#define A_PAD 11520
#define BK1 256
#define NC1 (DIM / BK1)     // 16 chunks, phase 1
#define NCH 6
#define KCH (A_PAD / NCH)   // 1920
#define NC2 (KCH / 64)      // 30 chunks, phase 2

#define GLOAD16(src, dst)                                                          \
  __builtin_amdgcn_global_load_lds(                                                \
      (__attribute__((address_space(1))) const void*)(src),                        \
      (__attribute__((address_space(3))) void*)(dst), 16, 0, 0)

#define WAITCNT(n) asm volatile("s_waitcnt vmcnt(" #n ")" ::: "memory")
#define BAR() __builtin_amdgcn_s_barrier()

// ---------------- pre-kernel: x fp32 -> bf16 ----------------
__global__ __launch_bounds__(256) void k_cvt_x(const float* __restrict__ x,
                                               bf16* __restrict__ xb) {
  int i = (blockIdx.x * 256 + threadIdx.x) * 8;
  f32x4 a = *(const f32x4*)(x + i);
  f32x4 b = *(const f32x4*)(x + i + 4);
  bf16x8 o;
  o[0] = (bf16)a[0]; o[1] = (bf16)a[1]; o[2] = (bf16)a[2]; o[3] = (bf16)a[3];
  o[4] = (bf16)b[0]; o[5] = (bf16)b[1]; o[6] = (bf16)b[2]; o[7] = (bf16)b[3];
  *(bf16x8*)(xb + i) = o;
}

// ---------------- phase 1: g_e = silu(x w1^T) * (x w3^T) * ew_e ----------------
// Block: 16 a-rows x 128 t. 4 waves, wave = M=32 t x N=16 a. BK=256 -> 1KB/row visit.
// LDS: 2 buffers x 32KB (w1 16x1KB | w3 16x1KB), XOR-swizzled via pre-swizzled source.
// 2 blocks/CU (phase-2's proven config). Per wave per chunk: 8 stage + 16 x loads.
__global__ __launch_bounds__(256, 2) void k_phase1(
    const bf16* __restrict__ xb,
    const float* __restrict__ w1e0, const float* __restrict__ w3e0,
    const float* __restrict__ w1e1, const float* __restrict__ w3e1,
    const float* __restrict__ ew, const int* __restrict__ ids,
    bf16* __restrict__ gws) {
  __shared__ __attribute__((aligned(16))) char smem[2][32768];
  const int e = blockIdx.y;
  const float* __restrict__ w1 = e ? w1e1 : w1e0;
  const float* __restrict__ w3 = e ? w3e1 : w3e0;
  bf16* __restrict__ g = gws + (size_t)e * T * A_PAD;

  const int tid = threadIdx.x;
  const int wv = tid >> 6;
  const int lane = tid & 63;
  const int ln = lane & 15;
  const int kh = lane >> 4;
  const int bx16 = blockIdx.x * 16;

  // wave wv stages 8 rows of (wv>>1 ? w3 : w1): rows (wv&1)*8 .. +7, 1KB each
  const char* wp = (const char*)((wv >> 1) ? w3 : w1);
  const int rbase = (wv & 1) * 8;
  const int moff = (wv >> 1) * 16384;  // w1 -> [0,16K), w3 -> [16K,32K)

  const bf16* __restrict__ px = xb + (size_t)(wv * 32 + ln) * DIM + kh * 8;
  const int swz = (ln & 7) << 4;

  f32x4 accu[2], accg[2];
  accu[0] = (f32x4){0,0,0,0}; accu[1] = (f32x4){0,0,0,0};
  accg[0] = (f32x4){0,0,0,0}; accg[1] = (f32x4){0,0,0,0};
  bf16x8 xf[2][8];

  auto STAGE = [&](int c, int b) {
    char* db = &smem[b][0] + moff;
    const char* wpc = wp + (size_t)c * 1024;  // chunk k-offset within row
#pragma unroll
    for (int i = 0; i < 8; ++i) {
      const int row = rbase + i;
      int grow = bx16 + row;
      grow = grow < NACT ? grow : NACT - 1;
      const char* src = wpc + (size_t)grow * (DIM * 4) +
                        ((lane * 16) ^ ((row & 7) << 4));
      GLOAD16(src, db + row * 1024);
    }
  };
  auto XLOAD = [&](int c) {
    const bf16* p = px + (size_t)c * BK1;
#pragma unroll
    for (int m = 0; m < 2; ++m)
#pragma unroll
      for (int ks = 0; ks < 8; ++ks)
        xf[m][ks] = *(const bf16x8*)(p + (size_t)m * 16 * DIM + ks * 32);
  };
  auto COMP = [&](int b) {
    const char* b1 = &smem[b][0] + (size_t)ln * 1024;
    const char* b3 = b1 + 16384;
#pragma unroll
    for (int ks = 0; ks < 8; ++ks) {
      const int o0 = (ks * 128 + kh * 32) ^ swz;
      const int o1 = (ks * 128 + kh * 32 + 16) ^ swz;
      f32x4 u0 = *(const f32x4*)(b1 + o0);
      f32x4 u1 = *(const f32x4*)(b1 + o1);
      f32x4 v0 = *(const f32x4*)(b3 + o0);
      f32x4 v1 = *(const f32x4*)(b3 + o1);
      bf16x8 f1, f3;
      f1[0] = (bf16)u0[0]; f1[1] = (bf16)u0[1]; f1[2] = (bf16)u0[2]; f1[3] = (bf16)u0[3];
      f1[4] = (bf16)u1[0]; f1[5] = (bf16)u1[1]; f1[6] = (bf16)u1[2]; f1[7] = (bf16)u1[3];
      f3[0] = (bf16)v0[0]; f3[1] = (bf16)v0[1]; f3[2] = (bf16)v0[2]; f3[3] = (bf16)v0[3];
      f3[4] = (bf16)v1[0]; f3[5] = (bf16)v1[1]; f3[6] = (bf16)v1[2]; f3[7] = (bf16)v1[3];
#pragma unroll
      for (int m = 0; m < 2; ++m) {
        accg[m] = __builtin_amdgcn_mfma_f32_16x16x32_bf16(xf[m][ks], f1, accg[m], 0, 0, 0);
        accu[m] = __builtin_amdgcn_mfma_f32_16x16x32_bf16(xf[m][ks], f3, accu[m], 0, 0, 0);
      }
    }
  };

  STAGE(0, 0);
  for (int c = 0; c < NC1; ++c) {
    const int b = c & 1;
    XLOAD(c);          // outstanding: S(c)8 + x16 = 24
    WAITCNT(16);       // retire S(c); keep x
    BAR();             // tile(c) ready everywhere; buf b^1 free
    if (c + 1 < NC1) {
      STAGE(c + 1, b ^ 1);  // outstanding: x16 + S(c+1)8
      WAITCNT(8);           // retire x(c); keep S(c+1) in flight across COMP
    } else {
      WAITCNT(0);
    }
    COMP(b);
  }

  // routing weights (swap if incoming expert_ids[0] != 0)
  float e0 = ew[0], e1 = ew[1];
  if (ids[0] != 0) { float t = e0; e0 = e1; e1 = t; }
  const float sel = e ? e1 : e0;
  const int a = bx16 + ln;
  const bool valid = a < NACT;

#pragma unroll
  for (int m = 0; m < 2; ++m) {
#pragma unroll
    for (int j = 0; j < 4; ++j) {
      const int t = wv * 32 + m * 16 + kh * 4 + j;  // C/D: row=(lane>>4)*4+j, col=lane&15
      float up = accu[m][j];
      float gt = accg[m][j];
      float sg = gt / (1.f + __expf(-gt));
      float val = valid ? sg * up * sel : 0.f;
      g[(size_t)t * A_PAD + a] = (bf16)val;
    }
  }
}

// ---------------- phase 2: out += sum_e g_e @ w2_e  (split-K, atomic fp32) ----------------
// Block: 128 t x 128 d. 4 waves, wave = M=32 t x N=128 d. Chunk = 64 k-rows,
// each w2 row visited in 512B contiguous spans. LDS: 2 x 32KB [64k][128d] f32.
// Counted-vmcnt: per wave per chunk 8 stage gload_lds + 4 g loads. (at roofline; keep)
__global__ __launch_bounds__(256, 2) void k_phase2(
    const bf16* __restrict__ gws,
    const float* __restrict__ w2e0, const float* __restrict__ w2e1,
    float* __restrict__ out) {
  __shared__ __attribute__((aligned(16))) char smem[2][32768];
  const int e = blockIdx.y / NCH;
  const int kc = blockIdx.y % NCH;
  const float* __restrict__ w2 = e ? w2e1 : w2e0;
  const bf16* __restrict__ g = gws + (size_t)e * T * A_PAD;

  const int tid = threadIdx.x;
  const int wv = tid >> 6;
  const int lane = tid & 63;
  const int ln = lane & 15;
  const int kh = lane >> 4;
  const int bx128 = blockIdx.x * 128;
  const int kcbase = kc * KCH;

  const bf16* __restrict__ pg = g + (size_t)(wv * 32 + ln) * A_PAD + kh * 8 + kcbase;

  f32x4 acc[2][8];
#pragma unroll
  for (int m = 0; m < 2; ++m)
#pragma unroll
    for (int n = 0; n < 8; ++n) acc[m][n] = (f32x4){0, 0, 0, 0};
  bf16x8 gf[2][2];

  auto STAGE2 = [&](int c, int b) {
    char* db = &smem[b][0] + (size_t)wv * 8192;
    const int kb = kcbase + c * 64;
#pragma unroll
    for (int i = 0; i < 8; ++i) {
      int kr = kb + (wv * 8 + i) * 2 + (lane >> 5);
      kr = kr < NACT ? kr : NACT - 1;  // dup row x g==0 pad -> 0 contribution
      const char* src = (const char*)w2 + ((size_t)kr * DIM + bx128) * 4 + (lane & 31) * 16;
      GLOAD16(src, db + i * 1024);
    }
  };
  auto GLOADG = [&](int c) {
    const bf16* p = pg + (size_t)c * 64;
#pragma unroll
    for (int m = 0; m < 2; ++m)
#pragma unroll
      for (int ks = 0; ks < 2; ++ks)
        gf[m][ks] = *(const bf16x8*)(p + (size_t)m * 16 * A_PAD + ks * 32);
  };
  auto COMP2 = [&](int b) {
    const char* base = &smem[b][0];
#pragma unroll
    for (int ks = 0; ks < 2; ++ks)
#pragma unroll
      for (int n = 0; n < 8; ++n) {
        bf16x8 wf;
#pragma unroll
        for (int j = 0; j < 8; ++j) {
          float f = *(const float*)(base + (ks * 32 + kh * 8 + j) * 512 + (n * 16 + ln) * 4);
          wf[j] = (bf16)f;
        }
#pragma unroll
        for (int m = 0; m < 2; ++m)
          acc[m][n] = __builtin_amdgcn_mfma_f32_16x16x32_bf16(gf[m][ks], wf, acc[m][n], 0, 0, 0);
      }
  };

  STAGE2(0, 0);
  for (int c = 0; c < NC2; ++c) {
    const int b = c & 1;
    GLOADG(c);         // outstanding: S(c)8 + g4
    WAITCNT(4);        // retire S(c); keep g
    BAR();
    if (c + 1 < NC2) {
      STAGE2(c + 1, b ^ 1);  // outstanding: g4 + S(c+1)8
      WAITCNT(8);            // retire g(c); keep S(c+1)
    } else {
      WAITCNT(0);
    }
    COMP2(b);
  }

  const int dbase = bx128 + ln;
#pragma unroll
  for (int m = 0; m < 2; ++m) {
#pragma unroll
    for (int n = 0; n < 8; ++n) {
#pragma unroll
      for (int j = 0; j < 4; ++j) {
        const int t = wv * 32 + m * 16 + kh * 4 + j;
        atomicAdd(out + (size_t)t * DIM + dbase + n * 16, acc[m][n][j]);
      }
    }
  }
}

// ---------------- launch ----------------
extern "C" void kernel_launch(void* const* d_in, const int* in_sizes, int n_in,
                              void* d_out, int out_size, void* d_ws, size_t ws_size,
                              hipStream_t stream) {
  const float* x    = (const float*)d_in[0];
  const float* ew   = (const float*)d_in[1];
  const int*   ids  = (const int*)d_in[2];
  const float* w1e0 = (const float*)d_in[3];
  const float* w3e0 = (const float*)d_in[4];
  const float* w2e0 = (const float*)d_in[5];
  const float* w1e1 = (const float*)d_in[6];
  const float* w3e1 = (const float*)d_in[7];
  const float* w2e1 = (const float*)d_in[8];
  float* out = (float*)d_out;

  bf16* xb = (bf16*)d_ws;                                   // 128*4096*2 = 1 MB
  bf16* g  = (bf16*)((char*)d_ws + (size_t)T * DIM * 2);    // 2 * 128*11520*2 = 5.9 MB

  hipMemsetAsync(d_out, 0, (size_t)T * DIM * sizeof(float), stream);
  k_cvt_x<<<dim3((T * DIM) / (256 * 8)), 256, 0, stream>>>(x, xb);
  k_phase1<<<dim3(A_PAD / 16, 2), 256, 0, stream>>>(xb, w1e0, w3e0, w1e1, w3e1, ew, ids, g);
  k_phase2<<<dim3(DIM / 128, 2 * NCH), 256, 0, stream>>>(g, w2e0, w2e1, out);
}

// Round 7
// 269.625 us; speedup vs baseline: 2.4615x; 1.2683x over previous
//
#include <hip/hip_runtime.h>

typedef __bf16 bf16;
typedef __attribute__((ext_vector_type(8))) __bf16 bf16x8;
typedef __attribute__((ext_vector_type(4))) float f32x4;

#define T 128
#define DIM 4096
#define NACT 11468
#define A_PAD 11520
#define BK1 128
#define NC1 (DIM / BK1)     // 32 chunks, phase 1
#define NCH 6
#define KCH (A_PAD / NCH)   // 1920
#define NC2 (KCH / 64)      // 30 chunks, phase 2

#define GLOAD16(src, dst)                                                          \
  __builtin_amdgcn_global_load_lds(                                                \
      (__attribute__((address_space(1))) const void*)(src),                        \
      (__attribute__((address_space(3))) void*)(dst), 16, 0, 0)

#define WAITCNT(n) asm volatile("s_waitcnt vmcnt(" #n ")" ::: "memory")
#define BAR() __builtin_amdgcn_s_barrier()

// ---------------- pre-kernel: x fp32 -> bf16 ----------------
__global__ __launch_bounds__(256) void k_cvt_x(const float* __restrict__ x,
                                               bf16* __restrict__ xb) {
  int i = (blockIdx.x * 256 + threadIdx.x) * 8;
  f32x4 a = *(const f32x4*)(x + i);
  f32x4 b = *(const f32x4*)(x + i + 4);
  bf16x8 o;
  o[0] = (bf16)a[0]; o[1] = (bf16)a[1]; o[2] = (bf16)a[2]; o[3] = (bf16)a[3];
  o[4] = (bf16)b[0]; o[5] = (bf16)b[1]; o[6] = (bf16)b[2]; o[7] = (bf16)b[3];
  *(bf16x8*)(xb + i) = o;
}

// ---------------- phase 1: g_e = silu(x w1^T) * (x w3^T) * ew_e ----------------
// Block: 32 a-rows x 128 t. 4 waves, wave = M=32 t x N=32 a (2 mf x 2 nf frags).
// BK=128 -> 512B/row visit (phase-2's). LDS: 2 buf x 32KB (w1 32x512B | w3 32x512B),
// XOR-swizzled via pre-swizzled source. 2 blocks/CU. Per wave per chunk: 8 stage
// gload_lds + 8 x loads; x is register-double-buffered and issued one chunk early
// so L2 latency hides under COMP+barrier.
__global__ __launch_bounds__(256, 2) void k_phase1(
    const bf16* __restrict__ xb,
    const float* __restrict__ w1e0, const float* __restrict__ w3e0,
    const float* __restrict__ w1e1, const float* __restrict__ w3e1,
    const float* __restrict__ ew, const int* __restrict__ ids,
    bf16* __restrict__ gws) {
  __shared__ __attribute__((aligned(16))) char smem[2][32768];
  const int e = blockIdx.y;
  const float* __restrict__ w1 = e ? w1e1 : w1e0;
  const float* __restrict__ w3 = e ? w3e1 : w3e0;
  bf16* __restrict__ g = gws + (size_t)e * T * A_PAD;

  const int tid = threadIdx.x;
  const int wv = tid >> 6;
  const int lane = tid & 63;
  const int ln = lane & 15;
  const int kh = lane >> 4;
  const int bx32 = blockIdx.x * 32;

  // staging: wave wv -> mat (wv>>1 ? w3 : w1), rows rb..rb+15; instr i covers
  // rows rb+i*2+(lane>>5), 512B each (one full BK-chunk span of that row)
  const char* wp = (const char*)((wv >> 1) ? w3 : w1);
  const int rb = (wv & 1) * 16;
  const int mo = (wv >> 1) * 16384;

  const char* sbase[8];
#pragma unroll
  for (int i = 0; i < 8; ++i) {
    const int row = rb + i * 2 + (lane >> 5);
    int grow = bx32 + row;
    grow = grow < NACT ? grow : NACT - 1;
    sbase[i] = wp + (size_t)grow * (DIM * 4) +
               (((lane & 31) * 16) ^ ((row & 7) << 4));  // pre-swizzled source
  }

  const bf16* __restrict__ px = xb + (size_t)(wv * 32 + ln) * DIM + kh * 8;
  const int swz = (ln & 7) << 4;

  f32x4 accu[2][2], accg[2][2];
#pragma unroll
  for (int mf = 0; mf < 2; ++mf)
#pragma unroll
    for (int nf = 0; nf < 2; ++nf) {
      accu[mf][nf] = (f32x4){0, 0, 0, 0};
      accg[mf][nf] = (f32x4){0, 0, 0, 0};
    }

  auto STAGE = [&](int c, int b) {
    char* db = &smem[b][0] + mo + rb * 512 + lane * 16;
    const size_t koff = (size_t)c * 512;
#pragma unroll
    for (int i = 0; i < 8; ++i) GLOAD16(sbase[i] + koff, db + i * 1024);
  };
  auto XLOAD = [&](bf16x8 (&xf)[8], int c) {
    const bf16* p = px + (size_t)c * BK1;
#pragma unroll
    for (int mf = 0; mf < 2; ++mf)
#pragma unroll
      for (int ks = 0; ks < 4; ++ks)
        xf[mf * 4 + ks] = *(const bf16x8*)(p + (size_t)mf * 16 * DIM + ks * 32);
  };
  auto COMP = [&](const bf16x8 (&xf)[8], int b) {
#pragma unroll
    for (int ks = 0; ks < 4; ++ks) {
      bf16x8 f1[2], f3[2];
#pragma unroll
      for (int nf = 0; nf < 2; ++nf) {
        const char* b1 = &smem[b][0] + (nf * 16 + ln) * 512;
        const char* b3 = b1 + 16384;
        const int o0 = (ks * 128 + kh * 32) ^ swz;
        const int o1 = (ks * 128 + kh * 32 + 16) ^ swz;
        f32x4 u0 = *(const f32x4*)(b1 + o0);
        f32x4 u1 = *(const f32x4*)(b1 + o1);
        f32x4 v0 = *(const f32x4*)(b3 + o0);
        f32x4 v1 = *(const f32x4*)(b3 + o1);
        f1[nf][0] = (bf16)u0[0]; f1[nf][1] = (bf16)u0[1];
        f1[nf][2] = (bf16)u0[2]; f1[nf][3] = (bf16)u0[3];
        f1[nf][4] = (bf16)u1[0]; f1[nf][5] = (bf16)u1[1];
        f1[nf][6] = (bf16)u1[2]; f1[nf][7] = (bf16)u1[3];
        f3[nf][0] = (bf16)v0[0]; f3[nf][1] = (bf16)v0[1];
        f3[nf][2] = (bf16)v0[2]; f3[nf][3] = (bf16)v0[3];
        f3[nf][4] = (bf16)v1[0]; f3[nf][5] = (bf16)v1[1];
        f3[nf][6] = (bf16)v1[2]; f3[nf][7] = (bf16)v1[3];
      }
#pragma unroll
      for (int mf = 0; mf < 2; ++mf)
#pragma unroll
        for (int nf = 0; nf < 2; ++nf) {
          accg[mf][nf] = __builtin_amdgcn_mfma_f32_16x16x32_bf16(xf[mf * 4 + ks], f1[nf], accg[mf][nf], 0, 0, 0);
          accu[mf][nf] = __builtin_amdgcn_mfma_f32_16x16x32_bf16(xf[mf * 4 + ks], f3[nf], accu[mf][nf], 0, 0, 0);
        }
    }
  };

  bf16x8 xfA[8], xfB[8];
  STAGE(0, 0);
  XLOAD(xfA, 0);

  for (int c = 0; c < NC1; c += 2) {
    // even chunk: x in A, buffer 0
    WAITCNT(8);                     // retire S(c); keep x(c)
    BAR();
    STAGE(c + 1, 1);
    XLOAD(xfB, c + 1);
    WAITCNT(16);                    // retire x(c); keep S(c+1)+x(c+1) in flight
    COMP(xfA, 0);
    // odd chunk: x in B, buffer 1
    WAITCNT(8);                     // retire S(c+1); keep x(c+1)
    BAR();
    if (c + 2 < NC1) {
      STAGE(c + 2, 0);
      XLOAD(xfA, c + 2);
      WAITCNT(16);                  // retire x(c+1)
    } else {
      WAITCNT(0);
    }
    COMP(xfB, 1);
  }

  // routing weights (swap if incoming expert_ids[0] != 0)
  float e0 = ew[0], e1 = ew[1];
  if (ids[0] != 0) { float t = e0; e0 = e1; e1 = t; }
  const float sel = e ? e1 : e0;

#pragma unroll
  for (int mf = 0; mf < 2; ++mf) {
#pragma unroll
    for (int nf = 0; nf < 2; ++nf) {
      const int a = bx32 + nf * 16 + ln;
      const bool valid = a < NACT;
#pragma unroll
      for (int j = 0; j < 4; ++j) {
        const int t = wv * 32 + mf * 16 + kh * 4 + j;  // C/D: row=(lane>>4)*4+j, col=lane&15
        float up = accu[mf][nf][j];
        float gt = accg[mf][nf][j];
        float sg = gt / (1.f + __expf(-gt));
        float val = valid ? sg * up * sel : 0.f;
        g[(size_t)t * A_PAD + a] = (bf16)val;
      }
    }
  }
}

// ---------------- phase 2: out += sum_e g_e @ w2_e  (split-K, atomic fp32) ----------------
// Block: 128 t x 128 d. 4 waves, wave = M=32 t x N=128 d. Chunk = 64 k-rows,
// each w2 row visited in 512B contiguous spans. LDS: 2 x 32KB [64k][128d] f32.
// Counted-vmcnt: per wave per chunk 8 stage gload_lds + 4 g loads. (at roofline; keep)
__global__ __launch_bounds__(256, 2) void k_phase2(
    const bf16* __restrict__ gws,
    const float* __restrict__ w2e0, const float* __restrict__ w2e1,
    float* __restrict__ out) {
  __shared__ __attribute__((aligned(16))) char smem[2][32768];
  const int e = blockIdx.y / NCH;
  const int kc = blockIdx.y % NCH;
  const float* __restrict__ w2 = e ? w2e1 : w2e0;
  const bf16* __restrict__ g = gws + (size_t)e * T * A_PAD;

  const int tid = threadIdx.x;
  const int wv = tid >> 6;
  const int lane = tid & 63;
  const int ln = lane & 15;
  const int kh = lane >> 4;
  const int bx128 = blockIdx.x * 128;
  const int kcbase = kc * KCH;

  const bf16* __restrict__ pg = g + (size_t)(wv * 32 + ln) * A_PAD + kh * 8 + kcbase;

  f32x4 acc[2][8];
#pragma unroll
  for (int m = 0; m < 2; ++m)
#pragma unroll
    for (int n = 0; n < 8; ++n) acc[m][n] = (f32x4){0, 0, 0, 0};
  bf16x8 gf[2][2];

  auto STAGE2 = [&](int c, int b) {
    char* db = &smem[b][0] + (size_t)wv * 8192;
    const int kb = kcbase + c * 64;
#pragma unroll
    for (int i = 0; i < 8; ++i) {
      int kr = kb + (wv * 8 + i) * 2 + (lane >> 5);
      kr = kr < NACT ? kr : NACT - 1;  // dup row x g==0 pad -> 0 contribution
      const char* src = (const char*)w2 + ((size_t)kr * DIM + bx128) * 4 + (lane & 31) * 16;
      GLOAD16(src, db + i * 1024);
    }
  };
  auto GLOADG = [&](int c) {
    const bf16* p = pg + (size_t)c * 64;
#pragma unroll
    for (int m = 0; m < 2; ++m)
#pragma unroll
      for (int ks = 0; ks < 2; ++ks)
        gf[m][ks] = *(const bf16x8*)(p + (size_t)m * 16 * A_PAD + ks * 32);
  };
  auto COMP2 = [&](int b) {
    const char* base = &smem[b][0];
#pragma unroll
    for (int ks = 0; ks < 2; ++ks)
#pragma unroll
      for (int n = 0; n < 8; ++n) {
        bf16x8 wf;
#pragma unroll
        for (int j = 0; j < 8; ++j) {
          float f = *(const float*)(base + (ks * 32 + kh * 8 + j) * 512 + (n * 16 + ln) * 4);
          wf[j] = (bf16)f;
        }
#pragma unroll
        for (int m = 0; m < 2; ++m)
          acc[m][n] = __builtin_amdgcn_mfma_f32_16x16x32_bf16(gf[m][ks], wf, acc[m][n], 0, 0, 0);
      }
  };

  STAGE2(0, 0);
  for (int c = 0; c < NC2; ++c) {
    const int b = c & 1;
    GLOADG(c);         // outstanding: S(c)8 + g4
    WAITCNT(4);        // retire S(c); keep g
    BAR();
    if (c + 1 < NC2) {
      STAGE2(c + 1, b ^ 1);  // outstanding: g4 + S(c+1)8
      WAITCNT(8);            // retire g(c); keep S(c+1)
    } else {
      WAITCNT(0);
    }
    COMP2(b);
  }

  const int dbase = bx128 + ln;
#pragma unroll
  for (int m = 0; m < 2; ++m) {
#pragma unroll
    for (int n = 0; n < 8; ++n) {
#pragma unroll
      for (int j = 0; j < 4; ++j) {
        const int t = wv * 32 + m * 16 + kh * 4 + j;
        atomicAdd(out + (size_t)t * DIM + dbase + n * 16, acc[m][n][j]);
      }
    }
  }
}

// ---------------- launch ----------------
extern "C" void kernel_launch(void* const* d_in, const int* in_sizes, int n_in,
                              void* d_out, int out_size, void* d_ws, size_t ws_size,
                              hipStream_t stream) {
  const float* x    = (const float*)d_in[0];
  const float* ew   = (const float*)d_in[1];
  const int*   ids  = (const int*)d_in[2];
  const float* w1e0 = (const float*)d_in[3];
  const float* w3e0 = (const float*)d_in[4];
  const float* w2e0 = (const float*)d_in[5];
  const float* w1e1 = (const float*)d_in[6];
  const float* w3e1 = (const float*)d_in[7];
  const float* w2e1 = (const float*)d_in[8];
  float* out = (float*)d_out;

  bf16* xb = (bf16*)d_ws;                                   // 128*4096*2 = 1 MB
  bf16* g  = (bf16*)((char*)d_ws + (size_t)T * DIM * 2);    // 2 * 128*11520*2 = 5.9 MB

  hipMemsetAsync(d_out, 0, (size_t)T * DIM * sizeof(float), stream);
  k_cvt_x<<<dim3((T * DIM) / (256 * 8)), 256, 0, stream>>>(x, xb);
  k_phase1<<<dim3(A_PAD / 32, 2), 256, 0, stream>>>(xb, w1e0, w3e0, w1e1, w3e1, ew, ids, g);
  k_phase2<<<dim3(DIM / 128, 2 * NCH), 256, 0, stream>>>(g, w2e0, w2e1, out);
}